// Round 13
// baseline (324.034 us; speedup 1.0000x reference)
//
#include <hip/hip_runtime.h>

// GCN regressor: 2x (mean-aggregate + linear+ReLU) + per-graph mean + MLP head.
// N=50000 nodes, E=800000 edges, D_IN=128, H1=256, H2=128, G=256.
// R13 = R12 with scan1+scan23 merged into ONE decoupled-lookback scan kernel
// (blocks wait only on lower-indexed blocks via release/acquire flags --
// pairwise ordering, NOT the all-to-all grid.sync that regressed R8/R9).
// Closed experiments (do not revisit):
//  - R6  chunked XCD-local gather: 7x regression (edge-list re-read, line split)
//  - R8/R9 cooperative grid.sync: 2x regression (device-scope drain per sync)
//  - R11 agg-into-GEMM fusion: occupancy 66->32% starved the gather (+40us)
// 9 dispatches: memset, misc(count+rank|gstart|h-cast|Wt1|Wt2), scan(lookback),
// scatter(no-atomic), agg128, gemm128, agg256, gemm256+readout, final.

#define NUM_GRAPHS 256

// misc_kernel block partition
#define CNT_B0 0
#define CNT_NB 1024
#define CST_B0 (CNT_B0 + CNT_NB)
#define CST_NB 512
#define GST_B0 (CST_B0 + CST_NB)
#define GST_NB 64
#define WT1_B0 (GST_B0 + GST_NB)
#define WT1_NB 16
#define WT2_B0 (WT1_B0 + WT1_NB)
#define WT2_NB 32
#define MISC_NB (WT2_B0 + WT2_NB)

typedef __attribute__((ext_vector_type(8))) short bf16x8;
typedef __attribute__((ext_vector_type(4))) float f32x4;

__device__ inline unsigned short f2bf(float f) {  // round-to-nearest-even
    unsigned u = __float_as_uint(f);
    return (unsigned short)((u + 0x7fff + ((u >> 16) & 1)) >> 16);
}
__device__ inline float bflo(unsigned u) { return __uint_as_float(u << 16); }
__device__ inline float bfhi(unsigned u) { return __uint_as_float(u & 0xffff0000u); }

// ---------------- misc: count+rank + gstart + h cast + weight transpose/cast ----------------

__launch_bounds__(256)
__global__ void misc_kernel(const int* __restrict__ dst, const int* __restrict__ gids,
                            const float* __restrict__ h,
                            const float* __restrict__ W1, const float* __restrict__ W2,
                            int* __restrict__ cnt, int* __restrict__ rank,
                            int* __restrict__ gstart,
                            unsigned short* __restrict__ hb,
                            unsigned short* __restrict__ Wt1, unsigned short* __restrict__ Wt2,
                            int N, int E) {
    int b = blockIdx.x, tid = threadIdx.x;
    if (b < CST_B0) {  // degree count + per-edge rank
        int lid = (b - CNT_B0) * 256 + tid;
        for (int e = lid; e < E; e += CNT_NB * 256) {
            int d = __builtin_nontemporal_load(&dst[e]);
            int r = atomicAdd(&cnt[d], 1);
            __builtin_nontemporal_store(r, &rank[e]);
        }
    } else if (b < GST_B0) {  // cast h -> bf16 (float4 granules)
        int lid = (b - CST_B0) * 256 + tid;
        int total4 = N * 32;
        for (int i = lid; i < total4; i += CST_NB * 256) {
            float4 v = *(const float4*)(h + (size_t)i * 4);
            ushort4 o;
            o.x = f2bf(v.x); o.y = f2bf(v.y); o.z = f2bf(v.z); o.w = f2bf(v.w);
            *(ushort4*)(hb + (size_t)i * 4) = o;
        }
    } else if (b < WT1_B0) {  // graph segment starts (gids sorted)
        int lid = (b - GST_B0) * 256 + tid;
        for (int n = lid; n < N; n += GST_NB * 256) {
            int g = gids[n];
            int gp = (n == 0) ? -1 : gids[n - 1];
            for (int x = gp + 1; x <= g; ++x) gstart[x] = n;
            if (n == N - 1)
                for (int x = g + 1; x <= NUM_GRAPHS; ++x) gstart[x] = N;
        }
    } else if (b < WT2_B0) {  // Wt1[n][k] = bf16(W1[k][n]), K=128
        int lid = (b - WT1_B0) * 256 + tid;
        for (int i = lid; i < 256 * 128; i += WT1_NB * 256)
            Wt1[i] = f2bf(W1[(size_t)(i & 127) * 256 + (i >> 7)]);
    } else {  // Wt2[n][k] = bf16(W2[k][n]), K=256
        int lid = (b - WT2_B0) * 256 + tid;
        for (int i = lid; i < 256 * 256; i += WT2_NB * 256)
            Wt2[i] = f2bf(W2[(size_t)(i & 255) * 256 + (i >> 8)]);
    }
}

// ---------------- single-kernel exclusive scan (decoupled lookback) ----------------
// 1024-thread blocks; block b publishes its total (release flag), then wave 0
// polls flags of blocks < b (one per lane, acquire via atomic RMW reads) and
// shuffle-reduces the base. Blocks only wait on lower indices -> progress
// guaranteed even under serialized dispatch. Requires gridDim.x <= 64.

__global__ void scan_kernel(const int* __restrict__ cnt, int* __restrict__ offs,
                            int* __restrict__ pval, int* __restrict__ pflag,
                            int N, int E) {
    __shared__ int wsum[16];
    __shared__ int sbase;
    int tid = threadIdx.x;
    int lane = tid & 63;
    int wid = tid >> 6;
    int b = blockIdx.x;
    int i = b * 1024 + tid;
    int v = (i < N) ? cnt[i] : 0;
    int x = v;
    #pragma unroll
    for (int d = 1; d < 64; d <<= 1) {
        int y = __shfl_up(x, d, 64);
        if (lane >= d) x += y;
    }
    if (lane == 63) wsum[wid] = x;
    __syncthreads();
    if (wid == 0) {
        int s = (lane < 16) ? wsum[lane] : 0;
        #pragma unroll
        for (int d = 1; d < 16; d <<= 1) {
            int y = __shfl_up(s, d, 64);
            if (lane >= d) s += y;
        }
        if (lane < 16) wsum[lane] = s;
    }
    __syncthreads();
    int wbase = (wid > 0) ? wsum[wid - 1] : 0;
    int ex = wbase + x - v;  // block-local exclusive

    // publish this block's total (release)
    if (tid == 1023) {
        pval[b] = wbase + x;
        __threadfence();
        atomicExch(&pflag[b], 1);
    }
    // lookback: wave 0, lane j handles predecessor j (b <= 63)
    if (wid == 0) {
        int sum = 0;
        if (lane < b) {
            while (atomicAdd(&pflag[lane], 0) == 0) {}
            sum = atomicAdd(&pval[lane], 0);  // acquire via RMW read
        }
        #pragma unroll
        for (int d = 32; d > 0; d >>= 1) sum += __shfl_xor(sum, d, 64);
        if (lane == 0) sbase = sum;
    }
    __syncthreads();
    if (i < N) offs[i] = sbase + ex;
    if (b == 0 && tid == 0) offs[N] = E;
}

// ---------------- scatter: no atomics (rank precomputed), nt streaming loads ----------------

__global__ void scatter_kernel(const int* __restrict__ src, const int* __restrict__ dst,
                               const int* __restrict__ offs, const int* __restrict__ rank,
                               int* __restrict__ eidx, int E) {
    int e = blockIdx.x * blockDim.x + threadIdx.x;
    if (e < E) {
        int d = __builtin_nontemporal_load(&dst[e]);
        int r = __builtin_nontemporal_load(&rank[e]);
        int s = __builtin_nontemporal_load(&src[e]);
        eidx[offs[d] + r] = s;
    }
}

// ---------------- mean aggregation: one wave per dst node, bf16 gather, fp32 accum ----------------
// 24 VGPR, no LDS, ~66% occupancy: the latency-bound gather's fuel is waves.

template <int D>
__global__ void agg_mean_bf16_kernel(const unsigned short* __restrict__ feat,
                                     const int* __restrict__ offs,
                                     const int* __restrict__ eidx,
                                     unsigned short* __restrict__ out, int N) {
    constexpr int VPL = D / 64;  // 2 or 4
    int wave = blockIdx.x * (blockDim.x >> 6) + (threadIdx.x >> 6);
    int lane = threadIdx.x & 63;
    if (wave >= N) return;
    int beg = offs[wave], end = offs[wave + 1];
    float acc[VPL];
    #pragma unroll
    for (int i = 0; i < VPL; ++i) acc[i] = 0.0f;

    int j = beg;
    for (; j + 8 <= end; j += 8) {
        int s[8];
        #pragma unroll
        for (int u = 0; u < 8; ++u) s[u] = eidx[j + u];
        if constexpr (VPL == 2) {
            unsigned v[8];
            #pragma unroll
            for (int u = 0; u < 8; ++u)
                v[u] = *(const unsigned*)(feat + (size_t)s[u] * D + lane * 2);
            #pragma unroll
            for (int u = 0; u < 8; ++u) { acc[0] += bflo(v[u]); acc[1] += bfhi(v[u]); }
        } else {
            uint2 v[8];
            #pragma unroll
            for (int u = 0; u < 8; ++u)
                v[u] = *(const uint2*)(feat + (size_t)s[u] * D + lane * 4);
            #pragma unroll
            for (int u = 0; u < 8; ++u) {
                acc[0] += bflo(v[u].x); acc[1] += bfhi(v[u].x);
                acc[2] += bflo(v[u].y); acc[3] += bfhi(v[u].y);
            }
        }
    }
    for (; j < end; ++j) {
        int s = eidx[j];
        if constexpr (VPL == 2) {
            unsigned v = *(const unsigned*)(feat + (size_t)s * D + lane * 2);
            acc[0] += bflo(v); acc[1] += bfhi(v);
        } else {
            uint2 v = *(const uint2*)(feat + (size_t)s * D + lane * 4);
            acc[0] += bflo(v.x); acc[1] += bfhi(v.x);
            acc[2] += bflo(v.y); acc[3] += bfhi(v.y);
        }
    }

    int deg = end - beg;
    float invd = 1.0f / (float)(deg > 0 ? deg : 1);
    unsigned short* orow = out + (size_t)wave * D + lane * VPL;
    if constexpr (VPL == 2) {
        ushort2 o; o.x = f2bf(acc[0] * invd); o.y = f2bf(acc[1] * invd);
        *(ushort2*)orow = o;
    } else {
        ushort4 o;
        o.x = f2bf(acc[0] * invd); o.y = f2bf(acc[1] * invd);
        o.z = f2bf(acc[2] * invd); o.w = f2bf(acc[3] * invd);
        *(ushort4*)orow = o;
    }
}

// ---------------- bf16 MFMA GEMM + bias + ReLU ----------------
// MODE 0: store bf16 to Cb.  MODE 1: fused per-graph-sum (sorted gids; local
// run accumulation per thread, atomic flush per run into gsum[g*256+col]).

template <int K, int MODE>
__launch_bounds__(256)
__global__ void gemm_mfma_kernel(const unsigned short* __restrict__ A,
                                 const unsigned short* __restrict__ Wt,
                                 const float* __restrict__ bias,
                                 unsigned short* __restrict__ Cb,
                                 const int* __restrict__ gids,
                                 float* __restrict__ gsum,
                                 int N) {
    constexpr int LDS = 40;
    __shared__ unsigned short As[64 * LDS];
    __shared__ unsigned short Bs[256 * LDS];

    int tid = threadIdx.x;
    int wave = tid >> 6;
    int lane = tid & 63;
    int m = lane & 15;
    int q = lane >> 4;
    int rowBase = blockIdx.x * 64;

    f32x4 acc[4][4] = {};

    for (int kc = 0; kc < K; kc += 32) {
        {
            int r = tid >> 2;
            int seg = tid & 3;
            int gr = rowBase + r;
            uint4 v = make_uint4(0, 0, 0, 0);
            if (gr < N) v = *(const uint4*)(A + (size_t)gr * K + kc + seg * 8);
            *(uint4*)&As[r * LDS + seg * 8] = v;
        }
        #pragma unroll
        for (int it = 0; it < 4; ++it) {
            int n = (tid >> 2) + it * 64;
            int seg = tid & 3;
            uint4 v = *(const uint4*)(Wt + (size_t)n * K + kc + seg * 8);
            *(uint4*)&Bs[n * LDS + seg * 8] = v;
        }
        __syncthreads();

        bf16x8 af[4], bfr[4];
        #pragma unroll
        for (int r = 0; r < 4; ++r)
            af[r] = *(const bf16x8*)&As[(r * 16 + m) * LDS + q * 8];
        #pragma unroll
        for (int c = 0; c < 4; ++c)
            bfr[c] = *(const bf16x8*)&Bs[(wave * 64 + c * 16 + m) * LDS + q * 8];
        #pragma unroll
        for (int r = 0; r < 4; ++r)
            #pragma unroll
            for (int c = 0; c < 4; ++c)
                acc[r][c] = __builtin_amdgcn_mfma_f32_16x16x32_bf16(af[r], bfr[c], acc[r][c], 0, 0, 0);
        __syncthreads();
    }

    if constexpr (MODE == 0) {
        #pragma unroll
        for (int c = 0; c < 4; ++c) {
            int col = wave * 64 + c * 16 + m;
            float bv = bias[col];
            #pragma unroll
            for (int r = 0; r < 4; ++r) {
                #pragma unroll
                for (int reg = 0; reg < 4; ++reg) {
                    int grow = rowBase + r * 16 + q * 4 + reg;
                    if (grow < N)
                        Cb[(size_t)grow * 256 + col] = f2bf(fmaxf(acc[r][c][reg] + bv, 0.0f));
                }
            }
        }
    } else {
        // stage this block's gids (rows visited in ascending order per thread)
        int* sgid = (int*)As;
        if (tid < 64) {
            int gr = rowBase + tid;
            sgid[tid] = (gr < N) ? gids[gr] : -1;
        }
        __syncthreads();
        #pragma unroll
        for (int c = 0; c < 4; ++c) {
            int col = wave * 64 + c * 16 + m;
            float bv = bias[col];
            float partsum = 0.0f;
            int gprev = -1;
            #pragma unroll
            for (int r = 0; r < 4; ++r) {
                #pragma unroll
                for (int reg = 0; reg < 4; ++reg) {
                    int lr = r * 16 + q * 4 + reg;
                    if (rowBase + lr < N) {
                        int g = sgid[lr];
                        float o = fmaxf(acc[r][c][reg] + bv, 0.0f);
                        if (g != gprev) {
                            if (gprev >= 0) atomicAdd(&gsum[gprev * 256 + col], partsum);
                            partsum = 0.0f;
                            gprev = g;
                        }
                        partsum += o;
                    }
                }
            }
            if (gprev >= 0) atomicAdd(&gsum[gprev * 256 + col], partsum);
        }
    }
}

// ---------------- MLP head ----------------

__global__ void final_kernel(const float* __restrict__ gsum, const int* __restrict__ gstart,
                             const float* __restrict__ Wr1, const float* __restrict__ br1,
                             const float* __restrict__ Wr2, const float* __restrict__ br2,
                             float* __restrict__ out) {
    int g = blockIdx.x;
    int j = threadIdx.x;  // 128
    int c = gstart[g + 1] - gstart[g];
    float invc = 1.0f / (float)(c > 0 ? c : 1);
    const float* gs = gsum + g * 256;
    float acc = br1[j];
    for (int k = 0; k < 256; ++k)
        acc += (gs[k] * invc) * Wr1[k * 128 + j];
    float p = acc * Wr2[j];
    #pragma unroll
    for (int d = 32; d > 0; d >>= 1) p += __shfl_down(p, d, 64);
    __shared__ float ws2[2];
    if ((j & 63) == 0) ws2[j >> 6] = p;
    __syncthreads();
    if (j == 0) out[g] = ws2[0] + ws2[1] + br2[0];
}

// ---------------- launch ----------------

extern "C" void kernel_launch(void* const* d_in, const int* in_sizes, int n_in,
                              void* d_out, int out_size, void* d_ws, size_t ws_size,
                              hipStream_t stream) {
    const float* h    = (const float*)d_in[0];
    const int*   src  = (const int*)d_in[1];
    const int*   dst  = (const int*)d_in[2];
    const int*   gids = (const int*)d_in[3];
    const float* W1   = (const float*)d_in[4];
    const float* b1   = (const float*)d_in[5];
    const float* W2   = (const float*)d_in[6];
    const float* b2   = (const float*)d_in[7];
    const float* Wr1  = (const float*)d_in[8];
    const float* br1  = (const float*)d_in[9];
    const float* Wr2  = (const float*)d_in[10];
    const float* br2  = (const float*)d_in[11];

    int N = in_sizes[0] / 128;
    int E = in_sizes[1];
    int nScanBlocks = (N + 1023) / 1024;  // 49 for N=50000; must be <= 64

    // workspace ([cnt|gsum|pflag] contiguous for a single memset)
    char* w = (char*)d_ws;
    unsigned short* hb     = (unsigned short*)w;  w += (size_t)N * 128 * sizeof(unsigned short);
    unsigned short* h1b    = (unsigned short*)w;  w += (size_t)N * 256 * sizeof(unsigned short);
    unsigned short* aggOut = (unsigned short*)w;  w += (size_t)N * 256 * sizeof(unsigned short);
    int* cnt    = (int*)w;              w += (size_t)N * sizeof(int);
    float* gsum = (float*)w;            w += (size_t)NUM_GRAPHS * 256 * sizeof(float);
    int* pflag  = (int*)w;              w += 64 * sizeof(int);
    int* pval   = (int*)w;              w += 64 * sizeof(int);
    int* offs   = (int*)w;              w += (size_t)(N + 1) * sizeof(int);
    int* eidx   = (int*)w;              w += (size_t)E * sizeof(int);
    int* rank   = (int*)w;              w += (size_t)E * sizeof(int);
    unsigned short* Wt1 = (unsigned short*)w;  w += 256 * 128 * sizeof(unsigned short);
    unsigned short* Wt2 = (unsigned short*)w;  w += 256 * 256 * sizeof(unsigned short);
    int* gstart = (int*)w;              w += (size_t)(NUM_GRAPHS + 1) * sizeof(int);

    // 1) zero cnt+gsum+pflag in one shot
    hipMemsetAsync(cnt, 0,
                   (size_t)N * sizeof(int) + (size_t)NUM_GRAPHS * 256 * sizeof(float) +
                   64 * sizeof(int),
                   stream);
    // 2) independent prep (count+rank, gstart, h cast, weight transposes)
    misc_kernel<<<MISC_NB, 256, 0, stream>>>(dst, gids, h, W1, W2, cnt, rank, gstart,
                                             hb, Wt1, Wt2, N, E);
    // 3) single-kernel decoupled-lookback scan
    scan_kernel<<<nScanBlocks, 1024, 0, stream>>>(cnt, offs, pval, pflag, N, E);
    // 4) scatter (atomic-free)
    scatter_kernel<<<(E + 255) / 256, 256, 0, stream>>>(src, dst, offs, rank, eidx, E);

    // 5-6) layer 1
    agg_mean_bf16_kernel<128><<<(N + 3) / 4, 256, 0, stream>>>(hb, offs, eidx, aggOut, N);
    gemm_mfma_kernel<128, 0><<<(N + 63) / 64, 256, 0, stream>>>(aggOut, Wt1, b1, h1b, nullptr, nullptr, N);

    // 7-8) layer 2 (readout fused into GEMM epilogue)
    agg_mean_bf16_kernel<256><<<(N + 3) / 4, 256, 0, stream>>>(h1b, offs, eidx, aggOut, N);
    gemm_mfma_kernel<256, 1><<<(N + 63) / 64, 256, 0, stream>>>(aggOut, Wt2, b2, nullptr, gids, gsum, N);

    // 9) head
    final_kernel<<<NUM_GRAPHS, 128, 0, stream>>>(gsum, gstart, Wr1, br1, Wr2, br2, (float*)d_out);
}

// Round 14
// 316.246 us; speedup vs baseline: 1.0246x; 1.0246x over previous
//
#include <hip/hip_runtime.h>

// GCN regressor: 2x (mean-aggregate + linear+ReLU) + per-graph mean + MLP head.
// N=50000 nodes, E=800000 edges, D_IN=128, H1=256, H2=128, G=256.
// R14 = R13 with eidx/rank narrowed to unsigned short (N<65536, deg<65536):
// halves scatter's random-write churn, rank traffic, and agg edge-list reads.
// Closed experiments (do not revisit):
//  - R6  chunked XCD-local gather: 7x regression (edge-list re-read, line split)
//  - R8/R9 cooperative grid.sync: 2x regression (device-scope drain per sync)
//  - R11 agg-into-GEMM fusion: occupancy 66->32% starved the gather (+40us)
//  - R13 dispatch-merge via lookback scan: neutral (gap savings =~ sync cost)
// agg256 pinned at ~57us / 3.57 TB/s / 174MB for 5 rounds = fabric floor for
// uniform-random 512B gathers on 8 non-coherent XCDs.

#define NUM_GRAPHS 256

// misc_kernel block partition
#define CNT_B0 0
#define CNT_NB 1024
#define CST_B0 (CNT_B0 + CNT_NB)
#define CST_NB 512
#define GST_B0 (CST_B0 + CST_NB)
#define GST_NB 64
#define WT1_B0 (GST_B0 + GST_NB)
#define WT1_NB 16
#define WT2_B0 (WT1_B0 + WT1_NB)
#define WT2_NB 32
#define MISC_NB (WT2_B0 + WT2_NB)

typedef __attribute__((ext_vector_type(8))) short bf16x8;
typedef __attribute__((ext_vector_type(4))) float f32x4;

__device__ inline unsigned short f2bf(float f) {  // round-to-nearest-even
    unsigned u = __float_as_uint(f);
    return (unsigned short)((u + 0x7fff + ((u >> 16) & 1)) >> 16);
}
__device__ inline float bflo(unsigned u) { return __uint_as_float(u << 16); }
__device__ inline float bfhi(unsigned u) { return __uint_as_float(u & 0xffff0000u); }

// ---------------- misc: count+rank + gstart + h cast + weight transpose/cast ----------------

__launch_bounds__(256)
__global__ void misc_kernel(const int* __restrict__ dst, const int* __restrict__ gids,
                            const float* __restrict__ h,
                            const float* __restrict__ W1, const float* __restrict__ W2,
                            int* __restrict__ cnt, unsigned short* __restrict__ rank,
                            int* __restrict__ gstart,
                            unsigned short* __restrict__ hb,
                            unsigned short* __restrict__ Wt1, unsigned short* __restrict__ Wt2,
                            int N, int E) {
    int b = blockIdx.x, tid = threadIdx.x;
    if (b < CST_B0) {  // degree count + per-edge rank (rank < deg_max << 65536)
        int lid = (b - CNT_B0) * 256 + tid;
        for (int e = lid; e < E; e += CNT_NB * 256) {
            int d = __builtin_nontemporal_load(&dst[e]);
            int r = atomicAdd(&cnt[d], 1);
            __builtin_nontemporal_store((unsigned short)r, &rank[e]);
        }
    } else if (b < GST_B0) {  // cast h -> bf16 (float4 granules)
        int lid = (b - CST_B0) * 256 + tid;
        int total4 = N * 32;
        for (int i = lid; i < total4; i += CST_NB * 256) {
            float4 v = *(const float4*)(h + (size_t)i * 4);
            ushort4 o;
            o.x = f2bf(v.x); o.y = f2bf(v.y); o.z = f2bf(v.z); o.w = f2bf(v.w);
            *(ushort4*)(hb + (size_t)i * 4) = o;
        }
    } else if (b < WT1_B0) {  // graph segment starts (gids sorted)
        int lid = (b - GST_B0) * 256 + tid;
        for (int n = lid; n < N; n += GST_NB * 256) {
            int g = gids[n];
            int gp = (n == 0) ? -1 : gids[n - 1];
            for (int x = gp + 1; x <= g; ++x) gstart[x] = n;
            if (n == N - 1)
                for (int x = g + 1; x <= NUM_GRAPHS; ++x) gstart[x] = N;
        }
    } else if (b < WT2_B0) {  // Wt1[n][k] = bf16(W1[k][n]), K=128
        int lid = (b - WT1_B0) * 256 + tid;
        for (int i = lid; i < 256 * 128; i += WT1_NB * 256)
            Wt1[i] = f2bf(W1[(size_t)(i & 127) * 256 + (i >> 7)]);
    } else {  // Wt2[n][k] = bf16(W2[k][n]), K=256
        int lid = (b - WT2_B0) * 256 + tid;
        for (int i = lid; i < 256 * 256; i += WT2_NB * 256)
            Wt2[i] = f2bf(W2[(size_t)(i & 255) * 256 + (i >> 8)]);
    }
}

// ---------------- single-kernel exclusive scan (decoupled lookback) ----------------

__global__ void scan_kernel(const int* __restrict__ cnt, int* __restrict__ offs,
                            int* __restrict__ pval, int* __restrict__ pflag,
                            int N, int E) {
    __shared__ int wsum[16];
    __shared__ int sbase;
    int tid = threadIdx.x;
    int lane = tid & 63;
    int wid = tid >> 6;
    int b = blockIdx.x;
    int i = b * 1024 + tid;
    int v = (i < N) ? cnt[i] : 0;
    int x = v;
    #pragma unroll
    for (int d = 1; d < 64; d <<= 1) {
        int y = __shfl_up(x, d, 64);
        if (lane >= d) x += y;
    }
    if (lane == 63) wsum[wid] = x;
    __syncthreads();
    if (wid == 0) {
        int s = (lane < 16) ? wsum[lane] : 0;
        #pragma unroll
        for (int d = 1; d < 16; d <<= 1) {
            int y = __shfl_up(s, d, 64);
            if (lane >= d) s += y;
        }
        if (lane < 16) wsum[lane] = s;
    }
    __syncthreads();
    int wbase = (wid > 0) ? wsum[wid - 1] : 0;
    int ex = wbase + x - v;  // block-local exclusive

    if (tid == 1023) {  // publish total (release)
        pval[b] = wbase + x;
        __threadfence();
        atomicExch(&pflag[b], 1);
    }
    if (wid == 0) {  // lookback: lane j polls predecessor j (gridDim <= 64)
        int sum = 0;
        if (lane < b) {
            while (atomicAdd(&pflag[lane], 0) == 0) {}
            sum = atomicAdd(&pval[lane], 0);
        }
        #pragma unroll
        for (int d = 32; d > 0; d >>= 1) sum += __shfl_xor(sum, d, 64);
        if (lane == 0) sbase = sum;
    }
    __syncthreads();
    if (i < N) offs[i] = sbase + ex;
    if (b == 0 && tid == 0) offs[N] = E;
}

// ---------------- scatter: no atomics, ushort targets, nt streaming loads ----------------

__global__ void scatter_kernel(const int* __restrict__ src, const int* __restrict__ dst,
                               const int* __restrict__ offs,
                               const unsigned short* __restrict__ rank,
                               unsigned short* __restrict__ eidx, int E) {
    int e = blockIdx.x * blockDim.x + threadIdx.x;
    if (e < E) {
        int d = __builtin_nontemporal_load(&dst[e]);
        unsigned short r = __builtin_nontemporal_load(&rank[e]);
        int s = __builtin_nontemporal_load(&src[e]);
        eidx[offs[d] + (int)r] = (unsigned short)s;
    }
}

// ---------------- mean aggregation: one wave per dst node, bf16 gather, fp32 accum ----------------
// 24 VGPR, no LDS, ~66% occupancy: the latency-bound gather's fuel is waves.

template <int D>
__global__ void agg_mean_bf16_kernel(const unsigned short* __restrict__ feat,
                                     const int* __restrict__ offs,
                                     const unsigned short* __restrict__ eidx,
                                     unsigned short* __restrict__ out, int N) {
    constexpr int VPL = D / 64;  // 2 or 4
    int wave = blockIdx.x * (blockDim.x >> 6) + (threadIdx.x >> 6);
    int lane = threadIdx.x & 63;
    if (wave >= N) return;
    int beg = offs[wave], end = offs[wave + 1];
    float acc[VPL];
    #pragma unroll
    for (int i = 0; i < VPL; ++i) acc[i] = 0.0f;

    int j = beg;
    for (; j + 8 <= end; j += 8) {
        int s[8];
        #pragma unroll
        for (int u = 0; u < 8; ++u) s[u] = (int)eidx[j + u];
        if constexpr (VPL == 2) {
            unsigned v[8];
            #pragma unroll
            for (int u = 0; u < 8; ++u)
                v[u] = *(const unsigned*)(feat + (size_t)s[u] * D + lane * 2);
            #pragma unroll
            for (int u = 0; u < 8; ++u) { acc[0] += bflo(v[u]); acc[1] += bfhi(v[u]); }
        } else {
            uint2 v[8];
            #pragma unroll
            for (int u = 0; u < 8; ++u)
                v[u] = *(const uint2*)(feat + (size_t)s[u] * D + lane * 4);
            #pragma unroll
            for (int u = 0; u < 8; ++u) {
                acc[0] += bflo(v[u].x); acc[1] += bfhi(v[u].x);
                acc[2] += bflo(v[u].y); acc[3] += bfhi(v[u].y);
            }
        }
    }
    for (; j < end; ++j) {
        int s = (int)eidx[j];
        if constexpr (VPL == 2) {
            unsigned v = *(const unsigned*)(feat + (size_t)s * D + lane * 2);
            acc[0] += bflo(v); acc[1] += bfhi(v);
        } else {
            uint2 v = *(const uint2*)(feat + (size_t)s * D + lane * 4);
            acc[0] += bflo(v.x); acc[1] += bfhi(v.x);
            acc[2] += bflo(v.y); acc[3] += bfhi(v.y);
        }
    }

    int deg = end - beg;
    float invd = 1.0f / (float)(deg > 0 ? deg : 1);
    unsigned short* orow = out + (size_t)wave * D + lane * VPL;
    if constexpr (VPL == 2) {
        ushort2 o; o.x = f2bf(acc[0] * invd); o.y = f2bf(acc[1] * invd);
        *(ushort2*)orow = o;
    } else {
        ushort4 o;
        o.x = f2bf(acc[0] * invd); o.y = f2bf(acc[1] * invd);
        o.z = f2bf(acc[2] * invd); o.w = f2bf(acc[3] * invd);
        *(ushort4*)orow = o;
    }
}

// ---------------- bf16 MFMA GEMM + bias + ReLU ----------------
// MODE 0: store bf16 to Cb.  MODE 1: fused per-graph-sum (sorted gids; local
// run accumulation per thread, atomic flush per run into gsum[g*256+col]).

template <int K, int MODE>
__launch_bounds__(256)
__global__ void gemm_mfma_kernel(const unsigned short* __restrict__ A,
                                 const unsigned short* __restrict__ Wt,
                                 const float* __restrict__ bias,
                                 unsigned short* __restrict__ Cb,
                                 const int* __restrict__ gids,
                                 float* __restrict__ gsum,
                                 int N) {
    constexpr int LDS = 40;
    __shared__ unsigned short As[64 * LDS];
    __shared__ unsigned short Bs[256 * LDS];

    int tid = threadIdx.x;
    int wave = tid >> 6;
    int lane = tid & 63;
    int m = lane & 15;
    int q = lane >> 4;
    int rowBase = blockIdx.x * 64;

    f32x4 acc[4][4] = {};

    for (int kc = 0; kc < K; kc += 32) {
        {
            int r = tid >> 2;
            int seg = tid & 3;
            int gr = rowBase + r;
            uint4 v = make_uint4(0, 0, 0, 0);
            if (gr < N) v = *(const uint4*)(A + (size_t)gr * K + kc + seg * 8);
            *(uint4*)&As[r * LDS + seg * 8] = v;
        }
        #pragma unroll
        for (int it = 0; it < 4; ++it) {
            int n = (tid >> 2) + it * 64;
            int seg = tid & 3;
            uint4 v = *(const uint4*)(Wt + (size_t)n * K + kc + seg * 8);
            *(uint4*)&Bs[n * LDS + seg * 8] = v;
        }
        __syncthreads();

        bf16x8 af[4], bfr[4];
        #pragma unroll
        for (int r = 0; r < 4; ++r)
            af[r] = *(const bf16x8*)&As[(r * 16 + m) * LDS + q * 8];
        #pragma unroll
        for (int c = 0; c < 4; ++c)
            bfr[c] = *(const bf16x8*)&Bs[(wave * 64 + c * 16 + m) * LDS + q * 8];
        #pragma unroll
        for (int r = 0; r < 4; ++r)
            #pragma unroll
            for (int c = 0; c < 4; ++c)
                acc[r][c] = __builtin_amdgcn_mfma_f32_16x16x32_bf16(af[r], bfr[c], acc[r][c], 0, 0, 0);
        __syncthreads();
    }

    if constexpr (MODE == 0) {
        #pragma unroll
        for (int c = 0; c < 4; ++c) {
            int col = wave * 64 + c * 16 + m;
            float bv = bias[col];
            #pragma unroll
            for (int r = 0; r < 4; ++r) {
                #pragma unroll
                for (int reg = 0; reg < 4; ++reg) {
                    int grow = rowBase + r * 16 + q * 4 + reg;
                    if (grow < N)
                        Cb[(size_t)grow * 256 + col] = f2bf(fmaxf(acc[r][c][reg] + bv, 0.0f));
                }
            }
        }
    } else {
        int* sgid = (int*)As;
        if (tid < 64) {
            int gr = rowBase + tid;
            sgid[tid] = (gr < N) ? gids[gr] : -1;
        }
        __syncthreads();
        #pragma unroll
        for (int c = 0; c < 4; ++c) {
            int col = wave * 64 + c * 16 + m;
            float bv = bias[col];
            float partsum = 0.0f;
            int gprev = -1;
            #pragma unroll
            for (int r = 0; r < 4; ++r) {
                #pragma unroll
                for (int reg = 0; reg < 4; ++reg) {
                    int lr = r * 16 + q * 4 + reg;
                    if (rowBase + lr < N) {
                        int g = sgid[lr];
                        float o = fmaxf(acc[r][c][reg] + bv, 0.0f);
                        if (g != gprev) {
                            if (gprev >= 0) atomicAdd(&gsum[gprev * 256 + col], partsum);
                            partsum = 0.0f;
                            gprev = g;
                        }
                        partsum += o;
                    }
                }
            }
            if (gprev >= 0) atomicAdd(&gsum[gprev * 256 + col], partsum);
        }
    }
}

// ---------------- MLP head ----------------

__global__ void final_kernel(const float* __restrict__ gsum, const int* __restrict__ gstart,
                             const float* __restrict__ Wr1, const float* __restrict__ br1,
                             const float* __restrict__ Wr2, const float* __restrict__ br2,
                             float* __restrict__ out) {
    int g = blockIdx.x;
    int j = threadIdx.x;  // 128
    int c = gstart[g + 1] - gstart[g];
    float invc = 1.0f / (float)(c > 0 ? c : 1);
    const float* gs = gsum + g * 256;
    float acc = br1[j];
    for (int k = 0; k < 256; ++k)
        acc += (gs[k] * invc) * Wr1[k * 128 + j];
    float p = acc * Wr2[j];
    #pragma unroll
    for (int d = 32; d > 0; d >>= 1) p += __shfl_down(p, d, 64);
    __shared__ float ws2[2];
    if ((j & 63) == 0) ws2[j >> 6] = p;
    __syncthreads();
    if (j == 0) out[g] = ws2[0] + ws2[1] + br2[0];
}

// ---------------- launch ----------------

extern "C" void kernel_launch(void* const* d_in, const int* in_sizes, int n_in,
                              void* d_out, int out_size, void* d_ws, size_t ws_size,
                              hipStream_t stream) {
    const float* h    = (const float*)d_in[0];
    const int*   src  = (const int*)d_in[1];
    const int*   dst  = (const int*)d_in[2];
    const int*   gids = (const int*)d_in[3];
    const float* W1   = (const float*)d_in[4];
    const float* b1   = (const float*)d_in[5];
    const float* W2   = (const float*)d_in[6];
    const float* b2   = (const float*)d_in[7];
    const float* Wr1  = (const float*)d_in[8];
    const float* br1  = (const float*)d_in[9];
    const float* Wr2  = (const float*)d_in[10];
    const float* br2  = (const float*)d_in[11];

    int N = in_sizes[0] / 128;
    int E = in_sizes[1];
    int nScanBlocks = (N + 1023) / 1024;  // 49 for N=50000; must be <= 64

    // workspace ([cnt|gsum|pflag] contiguous for a single memset)
    char* w = (char*)d_ws;
    unsigned short* hb     = (unsigned short*)w;  w += (size_t)N * 128 * sizeof(unsigned short);
    unsigned short* h1b    = (unsigned short*)w;  w += (size_t)N * 256 * sizeof(unsigned short);
    unsigned short* aggOut = (unsigned short*)w;  w += (size_t)N * 256 * sizeof(unsigned short);
    int* cnt    = (int*)w;              w += (size_t)N * sizeof(int);
    float* gsum = (float*)w;            w += (size_t)NUM_GRAPHS * 256 * sizeof(float);
    int* pflag  = (int*)w;              w += 64 * sizeof(int);
    int* pval   = (int*)w;              w += 64 * sizeof(int);
    int* offs   = (int*)w;              w += (size_t)(N + 1) * sizeof(int);
    unsigned short* eidx = (unsigned short*)w;  w += (size_t)E * sizeof(unsigned short);
    unsigned short* rank = (unsigned short*)w;  w += (size_t)E * sizeof(unsigned short);
    unsigned short* Wt1 = (unsigned short*)w;   w += 256 * 128 * sizeof(unsigned short);
    unsigned short* Wt2 = (unsigned short*)w;   w += 256 * 256 * sizeof(unsigned short);
    int* gstart = (int*)w;              w += (size_t)(NUM_GRAPHS + 1) * sizeof(int);

    // 1) zero cnt+gsum+pflag in one shot
    hipMemsetAsync(cnt, 0,
                   (size_t)N * sizeof(int) + (size_t)NUM_GRAPHS * 256 * sizeof(float) +
                   64 * sizeof(int),
                   stream);
    // 2) independent prep (count+rank, gstart, h cast, weight transposes)
    misc_kernel<<<MISC_NB, 256, 0, stream>>>(dst, gids, h, W1, W2, cnt, rank, gstart,
                                             hb, Wt1, Wt2, N, E);
    // 3) single-kernel decoupled-lookback scan
    scan_kernel<<<nScanBlocks, 1024, 0, stream>>>(cnt, offs, pval, pflag, N, E);
    // 4) scatter (atomic-free, ushort)
    scatter_kernel<<<(E + 255) / 256, 256, 0, stream>>>(src, dst, offs, rank, eidx, E);

    // 5-6) layer 1
    agg_mean_bf16_kernel<128><<<(N + 3) / 4, 256, 0, stream>>>(hb, offs, eidx, aggOut, N);
    gemm_mfma_kernel<128, 0><<<(N + 63) / 64, 256, 0, stream>>>(aggOut, Wt1, b1, h1b, nullptr, nullptr, N);

    // 7-8) layer 2 (readout fused into GEMM epilogue)
    agg_mean_bf16_kernel<256><<<(N + 3) / 4, 256, 0, stream>>>(h1b, offs, eidx, aggOut, N);
    gemm_mfma_kernel<256, 1><<<(N + 63) / 64, 256, 0, stream>>>(aggOut, Wt2, b2, nullptr, gids, gsum, N);

    // 9) head
    final_kernel<<<NUM_GRAPHS, 128, 0, stream>>>(gsum, gstart, Wr1, br1, Wr2, br2, (float*)d_out);
}